// Round 4
// baseline (413.268 us; speedup 1.0000x reference)
//
#include <hip/hip_runtime.h>
#include <cstdint>
#include <cstddef>

// B=2,S=1024 -> T=2048 tokens
#define T_TOK 2048
#define HDIM  1024
#define IDIM  2048
#define NEXP  8

#define BM 128
#define BK1 32          // gemm1 K-tile
#define BK2 32          // gemm2 K-tile
#define BN2 64          // gemm2 col tile
#define MAXPAD 3072
#define SH_TILES 16     // T_TOK/BM
#define RT_TILES 24     // MAXPAD/BM

typedef __attribute__((ext_vector_type(8))) short short8;
typedef __attribute__((ext_vector_type(4))) short short4v;
typedef __attribute__((ext_vector_type(4))) float float4v;

__device__ __forceinline__ short f2bf(float f) {
  uint32_t u = __float_as_uint(f);
  u += 0x7fffu + ((u >> 16) & 1u);
  return (short)(u >> 16);
}

__device__ __forceinline__ void gload_lds16(const void* g, void* l) {
  __builtin_amdgcn_global_load_lds(
      (const __attribute__((address_space(1))) uint32_t*)g,
      (__attribute__((address_space(3))) uint32_t*)l, 16, 0, 0);
}

// 16B-chunk XOR swizzle (self-inverse): bits[1:0] ^= bits[5:4].
// Staged with linear LDS dest + swizzled global source; fragment reads apply
// the same swizzle (rule #21). Valid for tiles up to 128 rows x 4 chunks.
__device__ __forceinline__ int swz(int c) { return c ^ ((c >> 4) & 3); }

// ---------------------------------------------------------------- small kernels

__global__ __launch_bounds__(256) void zero_init(int* __restrict__ counts,
                                                 int* __restrict__ perm) {
  int i = threadIdx.x;
  if (i < NEXP) counts[i] = 0;
  for (int p = i; p < MAXPAD; p += 256) perm[p] = 0;
}

// one wave per token: fp32 logits (exact argmax vs ref), score, bf16 copies
__global__ __launch_bounds__(256) void router_kernel(
    const float* __restrict__ x, const float* __restrict__ gw,
    short* __restrict__ xbf, short* __restrict__ xsbf,
    int* __restrict__ expert_id, int* __restrict__ slot,
    int* __restrict__ counts) {
  int wv = threadIdx.x >> 6, lane = threadIdx.x & 63;
  int t = blockIdx.x * 4 + wv;
  const float* xr = x + (size_t)t * HDIM;
  float4v xv[4];
  float lg[NEXP];
#pragma unroll
  for (int e = 0; e < NEXP; e++) lg[e] = 0.f;
#pragma unroll
  for (int p = 0; p < 4; p++) {
    xv[p] = *(const float4v*)(xr + p * 256 + lane * 4);
#pragma unroll
    for (int c = 0; c < 4; c++) {
      int h = p * 256 + lane * 4 + c;
      float4v g0 = *(const float4v*)(gw + (size_t)h * NEXP);
      float4v g1 = *(const float4v*)(gw + (size_t)h * NEXP + 4);
      float xc = xv[p][c];
      lg[0] += xc * g0[0]; lg[1] += xc * g0[1];
      lg[2] += xc * g0[2]; lg[3] += xc * g0[3];
      lg[4] += xc * g1[0]; lg[5] += xc * g1[1];
      lg[6] += xc * g1[2]; lg[7] += xc * g1[3];
    }
  }
#pragma unroll
  for (int ofs = 1; ofs < 64; ofs <<= 1) {
#pragma unroll
    for (int e = 0; e < NEXP; e++) lg[e] += __shfl_xor(lg[e], ofs, 64);
  }
  int be = 0;
  float bv = lg[0];
#pragma unroll
  for (int e = 1; e < NEXP; e++) {
    if (lg[e] > bv) { bv = lg[e]; be = e; }
  }
  float score = 1.f / (1.f + __expf(-bv));
  if (lane == 0) {
    expert_id[t] = be;
    slot[t] = atomicAdd(&counts[be], 1);
  }
#pragma unroll
  for (int p = 0; p < 4; p++) {
    short4v b, bs;
#pragma unroll
    for (int c = 0; c < 4; c++) {
      b[c] = f2bf(xv[p][c]);
      bs[c] = f2bf(xv[p][c] * score);
    }
    *(short4v*)(xbf + (size_t)t * HDIM + p * 256 + lane * 4) = b;
    *(short4v*)(xsbf + (size_t)t * HDIM + p * 256 + lane * 4) = bs;
  }
}

__global__ void prefix_kernel(const int* __restrict__ counts, int* __restrict__ pad_off) {
  if (threadIdx.x == 0 && blockIdx.x == 0) {
    int run = 0;
    for (int e = 0; e < NEXP; e++) {
      pad_off[e] = run;
      run += (counts[e] + BM - 1) & ~(BM - 1);
    }
    pad_off[NEXP] = run;
  }
}

__global__ __launch_bounds__(256) void build_perm(
    const int* __restrict__ expert_id, const int* __restrict__ slot,
    const int* __restrict__ pad_off, int* __restrict__ perm) {
  int t = blockIdx.x * 256 + threadIdx.x;
  int e = expert_id[t];
  perm[pad_off[e] + slot[t]] = t;
}

// ---------------------------------------------------------------- weight transpose+convert
// No-LDS streaming transpose: each thread owns a 4n x 8k micro-tile in
// registers. Reads: 8x float4 (16-lane group = 256B contiguous per row).
// Writes: 4x short8 (16B of k-contiguous bf16; 4 kgroups/wave tile a full
// 64B line per output row). No barriers, no LDS, no scalar LDS reads (the
// previous version's 16x ds_read_u16 + 2 barriers capped it at 2.5 TB/s).
// Flat 1-D grid over all 27 matrices:
//   blocks [0, 18*256): w1-type  src fp32 [1024][2048] -> dst bf16 [2048][1024]
//   blocks [18*256, +9*256): w2  src fp32 [2048][1024] -> dst bf16 [1024][2048]
// Block tile: 64 n-cols x 128 k-rows (4 waves stacked along k).

__global__ __launch_bounds__(256) void transpose_all(
    const float* __restrict__ shg, const float* __restrict__ shu,
    const float* __restrict__ rtg, const float* __restrict__ rtu,
    short* __restrict__ shg_t, short* __restrict__ shu_t,
    short* __restrict__ rtg_t, short* __restrict__ rtu_t,
    const float* __restrict__ shd, const float* __restrict__ rtd,
    short* __restrict__ shd_t, short* __restrict__ rtd_t) {
  int bid = blockIdx.x;
  const float* s;
  short* d;
  int R, C, tile_n, tile_r;
  if (bid < 18 * 256) {
    int m = bid >> 8, w = bid & 255;
    R = HDIM; C = IDIM;                 // src [R][C], dst [C][R]
    if (m == 0)      { s = shg; d = shg_t; }
    else if (m == 1) { s = shu; d = shu_t; }
    else if (m < 10) { size_t o = (size_t)(m - 2) * HDIM * IDIM; s = rtg + o; d = rtg_t + o; }
    else             { size_t o = (size_t)(m - 10) * HDIM * IDIM; s = rtu + o; d = rtu_t + o; }
    tile_n = w >> 3;                    // 0..31  (C/64)
    tile_r = w & 7;                     // 0..7   (R/128)
  } else {
    int b2 = bid - 18 * 256;
    int m = b2 >> 8, w = b2 & 255;
    R = IDIM; C = HDIM;
    if (m == 0) { s = shd; d = shd_t; }
    else        { size_t o = (size_t)(m - 1) * IDIM * HDIM; s = rtd + o; d = rtd_t + o; }
    tile_n = w >> 4;                    // 0..15 (C/64)
    tile_r = w & 15;                    // 0..15 (R/128)
  }
  int lane = threadIdx.x & 63, wv = threadIdx.x >> 6;
  int n0 = tile_n * 64 + (lane & 15) * 4;
  int k0 = tile_r * 128 + wv * 32 + (lane >> 4) * 8;
  float4v v[8];
#pragma unroll
  for (int j = 0; j < 8; j++)
    v[j] = *(const float4v*)(s + (size_t)(k0 + j) * C + n0);
#pragma unroll
  for (int i = 0; i < 4; i++) {
    short8 o;
#pragma unroll
    for (int j = 0; j < 8; j++) o[j] = f2bf(v[j][i]);
    *(short8*)(d + (size_t)(n0 + i) * R + k0) = o;
  }
}

// ---------------------------------------------------------------- gemm1: act = silu(A Wg) * (A Wu)
// A bf16 [rows][1024]; B^T bf16 [2048 n][1024 k].
// 512 threads / 8 waves (2x4), wave owns 64x32 -> dual acc = 64 VGPR.
// 3-buffer K-pipeline, counted vmcnt(3) + raw s_barrier: loads stay 2 K-steps
// in flight, never drained in the loop (T3+T4). One barrier per K-step.
// setprio around MFMA (T5).
// grid y: [0,16) shared tiles, [16,40) routed padded tiles.

#define G1_STAGE(b, kk) do { \
    gload_lds16(A + gA + (kk), sA[b] + tid * 8);   \
    gload_lds16(Bg + gB + (kk), sBg[b] + tid * 8); \
    gload_lds16(Bu + gB + (kk), sBu[b] + tid * 8); } while (0)

__global__ __launch_bounds__(512, 2) void gemm1_swiglu(
    const short* __restrict__ xbf, const short* __restrict__ xsbf,
    const short* __restrict__ shg_t, const short* __restrict__ shu_t,
    const short* __restrict__ rtg_t, const short* __restrict__ rtu_t,
    short* __restrict__ act_sh, short* __restrict__ act_rt,
    const int* __restrict__ pad_off, const int* __restrict__ perm) {
  __shared__ __align__(1024) short sA[3][BM * BK1];
  __shared__ __align__(1024) short sBg[3][BM * BK1];
  __shared__ __align__(1024) short sBu[3][BM * BK1];
  int tid = threadIdx.x, lane = tid & 63, wv = tid >> 6;
  int C0 = blockIdx.x * 128;
  int y = blockIdx.y;
  const short *A, *Bg, *Bu;
  short* act;
  int R0;
  bool routed = (y >= SH_TILES);
  if (!routed) {
    A = xbf; Bg = shg_t; Bu = shu_t; act = act_sh; R0 = y * BM;
  } else {
    R0 = (y - SH_TILES) * BM;
    if (R0 >= pad_off[NEXP]) return;
    int e = 0;
    while (pad_off[e + 1] <= R0) e++;
    size_t o = (size_t)e * HDIM * IDIM;
    A = xsbf; Bg = rtg_t + o; Bu = rtu_t + o; act = act_rt;
  }
  // staging: tile = 512 chunks of 16B, one chunk per thread per tile.
  int c0 = swz(tid);
  int r0c = c0 >> 2;
  int ar0 = routed ? perm[R0 + r0c] : R0 + r0c;
  size_t gA = (size_t)ar0 * HDIM + (c0 & 3) * 8;
  size_t gB = (size_t)(C0 + r0c) * HDIM + (c0 & 3) * 8;

  float4v accg[4][2], accu[4][2];
  float4v z4 = {0.f, 0.f, 0.f, 0.f};
#pragma unroll
  for (int i = 0; i < 4; i++)
#pragma unroll
    for (int j = 0; j < 2; j++) { accg[i][j] = z4; accu[i][j] = z4; }

  const int wrow = (wv >> 2) * 64, wcol = (wv & 3) * 32;
  const int mrow = lane & 15, h4 = lane >> 4;
  int aoff[4], boff[2];
#pragma unroll
  for (int i = 0; i < 4; i++)
    aoff[i] = swz(((wrow + i * 16 + mrow) << 2) + h4) * 8;
#pragma unroll
  for (int j = 0; j < 2; j++)
    boff[j] = swz(((wcol + j * 16 + mrow) << 2) + h4) * 8;

  // prologue: 2 K-steps in flight
  G1_STAGE(0, 0);
  G1_STAGE(1, BK1);

  int cur = 0;
  for (int k0 = 0; k0 < HDIM; k0 += BK1) {
    if (k0 + BK1 < HDIM) {
      asm volatile("s_waitcnt vmcnt(3)" ::: "memory");   // this step's stage done
    } else {
      asm volatile("s_waitcnt vmcnt(0)" ::: "memory");   // final: drain
    }
    __builtin_amdgcn_s_barrier();
    int k2 = k0 + 2 * BK1;
    if (k2 < HDIM) {
      int nb = cur + 2; if (nb >= 3) nb -= 3;
      G1_STAGE(nb, k2);               // overwrites buf last read at iter-1; safe after barrier
    }
    const short* cA = sA[cur];
    const short* cG = sBg[cur];
    const short* cU = sBu[cur];
    short8 af[4], bg[2], bu[2];
#pragma unroll
    for (int i = 0; i < 4; i++) af[i] = *(const short8*)(cA + aoff[i]);
#pragma unroll
    for (int j = 0; j < 2; j++) {
      bg[j] = *(const short8*)(cG + boff[j]);
      bu[j] = *(const short8*)(cU + boff[j]);
    }
    __builtin_amdgcn_s_setprio(1);
#pragma unroll
    for (int i = 0; i < 4; i++)
#pragma unroll
      for (int j = 0; j < 2; j++) {
        accg[i][j] = __builtin_amdgcn_mfma_f32_16x16x32_bf16(af[i], bg[j], accg[i][j], 0, 0, 0);
        accu[i][j] = __builtin_amdgcn_mfma_f32_16x16x32_bf16(af[i], bu[j], accu[i][j], 0, 0, 0);
      }
    __builtin_amdgcn_s_setprio(0);
    cur = (cur == 2) ? 0 : cur + 1;
  }
  int qrow = h4 * 4, col = mrow;
#pragma unroll
  for (int i = 0; i < 4; i++)
#pragma unroll
    for (int j = 0; j < 2; j++)
#pragma unroll
      for (int r = 0; r < 4; r++) {
        int row = R0 + wrow + i * 16 + qrow + r;
        int c = C0 + wcol + j * 16 + col;
        float g = accg[i][j][r], u = accu[i][j][r];
        float sv = g / (1.f + __expf(-g)) * u;
        act[(size_t)row * IDIM + c] = f2bf(sv);
      }
}

// ---------------------------------------------------------------- gemm2: out = act Wd^T-form
// A bf16 [rows][2048]; B^T bf16 [1024 n][2048 k]. 256 thr / 4 waves, tile
// 128x64, BK=32, same 3-buffer counted-vmcnt pipeline.
// shared tiles -> plain store to out; routed -> scatter to rt_out; add kernel combines.

#define G2_STAGE(b, kk) do { \
    gload_lds16(A + gA0 + (kk), sA[b] + tid * 8);         \
    gload_lds16(A + gA1 + (kk), sA[b] + (tid + 256) * 8); \
    gload_lds16(Bd + gB0 + (kk), sB[b] + tid * 8); } while (0)

__global__ __launch_bounds__(256, 4) void gemm2_down(
    const short* __restrict__ act_sh, const short* __restrict__ act_rt,
    const short* __restrict__ shd_t, const short* __restrict__ rtd_t,
    float* __restrict__ out, float* __restrict__ rt_out,
    const int* __restrict__ pad_off, const int* __restrict__ counts,
    const int* __restrict__ perm) {
  __shared__ __align__(1024) short sA[3][BM * BK2];
  __shared__ __align__(1024) short sB[3][BN2 * BK2];
  int tid = threadIdx.x, lane = tid & 63, wv = tid >> 6;
  int C0 = blockIdx.x * BN2;
  int y = blockIdx.y;
  const short *A, *Bd;
  int R0, e = 0;
  bool routed = (y >= SH_TILES);
  if (!routed) {
    A = act_sh; Bd = shd_t; R0 = y * BM;
  } else {
    R0 = (y - SH_TILES) * BM;
    if (R0 >= pad_off[NEXP]) return;
    while (pad_off[e + 1] <= R0) e++;
    A = act_rt; Bd = rtd_t + (size_t)e * IDIM * HDIM;
  }
  // A tile 128x32 = 512 chunks (2/thread); B tile 64x32 = 256 chunks (1/thread)
  int cA0 = swz(tid), cA1 = swz(tid + 256), cB = swz(tid);
  size_t gA0 = (size_t)(R0 + (cA0 >> 2)) * IDIM + (cA0 & 3) * 8;
  size_t gA1 = (size_t)(R0 + (cA1 >> 2)) * IDIM + (cA1 & 3) * 8;
  size_t gB0 = (size_t)(C0 + (cB >> 2)) * IDIM + (cB & 3) * 8;

  float4v acc[2][4];
  float4v z4 = {0.f, 0.f, 0.f, 0.f};
#pragma unroll
  for (int i = 0; i < 2; i++)
#pragma unroll
    for (int j = 0; j < 4; j++) acc[i][j] = z4;

  const int wrow = wv * 32;
  const int mrow = lane & 15, h4 = lane >> 4;
  int aoff[2], boff[4];
#pragma unroll
  for (int i = 0; i < 2; i++)
    aoff[i] = swz(((wrow + i * 16 + mrow) << 2) + h4) * 8;
#pragma unroll
  for (int j = 0; j < 4; j++)
    boff[j] = swz(((j * 16 + mrow) << 2) + h4) * 8;

  G2_STAGE(0, 0);
  G2_STAGE(1, BK2);

  int cur = 0;
  for (int k0 = 0; k0 < IDIM; k0 += BK2) {
    if (k0 + BK2 < IDIM) {
      asm volatile("s_waitcnt vmcnt(3)" ::: "memory");
    } else {
      asm volatile("s_waitcnt vmcnt(0)" ::: "memory");
    }
    __builtin_amdgcn_s_barrier();
    int k2 = k0 + 2 * BK2;
    if (k2 < IDIM) {
      int nb = cur + 2; if (nb >= 3) nb -= 3;
      G2_STAGE(nb, k2);
    }
    const short* cAp = sA[cur];
    const short* cBp = sB[cur];
    short8 af[2], bf4[4];
#pragma unroll
    for (int i = 0; i < 2; i++) af[i] = *(const short8*)(cAp + aoff[i]);
#pragma unroll
    for (int j = 0; j < 4; j++) bf4[j] = *(const short8*)(cBp + boff[j]);
    __builtin_amdgcn_s_setprio(1);
#pragma unroll
    for (int i = 0; i < 2; i++)
#pragma unroll
      for (int j = 0; j < 4; j++)
        acc[i][j] = __builtin_amdgcn_mfma_f32_16x16x32_bf16(af[i], bf4[j], acc[i][j], 0, 0, 0);
    __builtin_amdgcn_s_setprio(0);
    cur = (cur == 2) ? 0 : cur + 1;
  }
  int qrow = h4 * 4, col = mrow;
#pragma unroll
  for (int i = 0; i < 2; i++)
#pragma unroll
    for (int j = 0; j < 4; j++)
#pragma unroll
      for (int r = 0; r < 4; r++) {
        int row = R0 + wrow + i * 16 + qrow + r;
        int c = C0 + j * 16 + col;
        float v = acc[i][j][r];
        if (!routed) {
          out[(size_t)row * HDIM + c] = v;
        } else if (row - pad_off[e] < counts[e]) {
          rt_out[(size_t)perm[row] * HDIM + c] = v;
        }
      }
}

__global__ __launch_bounds__(256) void add_routed(float* __restrict__ out,
                                                  const float* __restrict__ rt_out) {
  size_t i = ((size_t)blockIdx.x * 256 + threadIdx.x) * 4;
  float4v a = *(const float4v*)(out + i);
  float4v b = *(const float4v*)(rt_out + i);
  a[0] += b[0]; a[1] += b[1]; a[2] += b[2]; a[3] += b[3];
  *(float4v*)(out + i) = a;
}

// ---------------------------------------------------------------- launch

extern "C" void kernel_launch(void* const* d_in, const int* in_sizes, int n_in,
                              void* d_out, int out_size, void* d_ws, size_t ws_size,
                              hipStream_t stream) {
  const float* x       = (const float*)d_in[0];
  const float* gate_w  = (const float*)d_in[1];
  const float* sh_gate = (const float*)d_in[2];
  const float* sh_up   = (const float*)d_in[3];
  const float* sh_down = (const float*)d_in[4];
  const float* rt_gate = (const float*)d_in[5];
  const float* rt_up   = (const float*)d_in[6];
  const float* rt_down = (const float*)d_in[7];
  float* out = (float*)d_out;

  char* w = (char*)d_ws;
  const size_t MB = 1024 * 1024;
  short* xbf    = (short*)(w + 0 * MB);    // 4 MB  [2048][1024] bf16
  short* xsbf   = (short*)(w + 4 * MB);    // 4 MB
  short* act_sh = (short*)(w + 8 * MB);    // 8 MB  [2048][2048]
  short* act_rt = (short*)(w + 16 * MB);   // 12 MB [3072][2048]
  float* rt_out = (float*)(w + 28 * MB);   // 8 MB  [2048][1024] fp32
  short* shg_t  = (short*)(w + 36 * MB);   // 4 MB  [2048][1024]
  short* shu_t  = (short*)(w + 40 * MB);   // 4 MB
  short* shd_t  = (short*)(w + 44 * MB);   // 4 MB  [1024][2048]
  short* rtg_t  = (short*)(w + 48 * MB);   // 32 MB [8][2048][1024]
  short* rtu_t  = (short*)(w + 80 * MB);   // 32 MB
  short* rtd_t  = (short*)(w + 112 * MB);  // 32 MB [8][1024][2048]
  int* ints     = (int*)(w + 144 * MB);
  int* counts    = ints;
  int* pad_off   = ints + 8;
  int* expert_id = ints + 32;
  int* slot      = ints + 32 + 2048;
  int* perm      = ints + 32 + 4096;

  zero_init<<<1, 256, 0, stream>>>(counts, perm);
  router_kernel<<<T_TOK / 4, 256, 0, stream>>>(x, gate_w, xbf, xsbf, expert_id, slot, counts);
  prefix_kernel<<<1, 64, 0, stream>>>(counts, pad_off);
  build_perm<<<T_TOK / 256, 256, 0, stream>>>(expert_id, slot, pad_off, perm);

  transpose_all<<<18 * 256 + 9 * 256, 256, 0, stream>>>(
      sh_gate, sh_up, rt_gate, rt_up, shg_t, shu_t, rtg_t, rtu_t,
      sh_down, rt_down, shd_t, rtd_t);

  gemm1_swiglu<<<dim3(IDIM / 128, SH_TILES + RT_TILES), 512, 0, stream>>>(
      xbf, xsbf, shg_t, shu_t, rtg_t, rtu_t, act_sh, act_rt, pad_off, perm);

  gemm2_down<<<dim3(HDIM / BN2, SH_TILES + RT_TILES), 256, 0, stream>>>(
      act_sh, act_rt, shd_t, rtd_t, out, rt_out, pad_off, counts, perm);

  add_routed<<<(T_TOK * HDIM) / (256 * 4), 256, 0, stream>>>(out, rt_out);
}

// Round 5
// 412.125 us; speedup vs baseline: 1.0028x; 1.0028x over previous
//
#include <hip/hip_runtime.h>
#include <cstdint>
#include <cstddef>

// B=2,S=1024 -> T=2048 tokens
#define T_TOK 2048
#define HDIM  1024
#define IDIM  2048
#define NEXP  8

#define BM 128
#define BK1 32          // gemm1 K-tile
#define BK2 32          // gemm2 K-tile
#define BN2 64          // gemm2 col tile
#define MAXPAD 3072
#define SH_TILES 16     // T_TOK/BM
#define RT_TILES 24     // MAXPAD/BM

typedef __attribute__((ext_vector_type(8))) short short8;
typedef __attribute__((ext_vector_type(4))) short short4v;
typedef __attribute__((ext_vector_type(4))) float float4v;

__device__ __forceinline__ short f2bf(float f) {
  uint32_t u = __float_as_uint(f);
  u += 0x7fffu + ((u >> 16) & 1u);
  return (short)(u >> 16);
}

__device__ __forceinline__ void gload_lds16(const void* g, void* l) {
  __builtin_amdgcn_global_load_lds(
      (const __attribute__((address_space(1))) uint32_t*)g,
      (__attribute__((address_space(3))) uint32_t*)l, 16, 0, 0);
}

// 16B-chunk XOR swizzle (self-inverse): bits[1:0] ^= bits[5:4].
__device__ __forceinline__ int swz(int c) { return c ^ ((c >> 4) & 3); }

// ---------------------------------------------------------------- small kernels

__global__ __launch_bounds__(256) void zero_init(int* __restrict__ counts,
                                                 int* __restrict__ perm) {
  int i = threadIdx.x;
  if (i < NEXP) counts[i] = 0;
  for (int p = i; p < MAXPAD; p += 256) perm[p] = 0;
}

// one wave per token: fp32 logits (exact argmax vs ref), score, bf16 copies
__global__ __launch_bounds__(256) void router_kernel(
    const float* __restrict__ x, const float* __restrict__ gw,
    short* __restrict__ xbf, short* __restrict__ xsbf,
    int* __restrict__ expert_id, int* __restrict__ slot,
    int* __restrict__ counts) {
  int wv = threadIdx.x >> 6, lane = threadIdx.x & 63;
  int t = blockIdx.x * 4 + wv;
  const float* xr = x + (size_t)t * HDIM;
  float4v xv[4];
  float lg[NEXP];
#pragma unroll
  for (int e = 0; e < NEXP; e++) lg[e] = 0.f;
#pragma unroll
  for (int p = 0; p < 4; p++) {
    xv[p] = *(const float4v*)(xr + p * 256 + lane * 4);
#pragma unroll
    for (int c = 0; c < 4; c++) {
      int h = p * 256 + lane * 4 + c;
      float4v g0 = *(const float4v*)(gw + (size_t)h * NEXP);
      float4v g1 = *(const float4v*)(gw + (size_t)h * NEXP + 4);
      float xc = xv[p][c];
      lg[0] += xc * g0[0]; lg[1] += xc * g0[1];
      lg[2] += xc * g0[2]; lg[3] += xc * g0[3];
      lg[4] += xc * g1[0]; lg[5] += xc * g1[1];
      lg[6] += xc * g1[2]; lg[7] += xc * g1[3];
    }
  }
#pragma unroll
  for (int ofs = 1; ofs < 64; ofs <<= 1) {
#pragma unroll
    for (int e = 0; e < NEXP; e++) lg[e] += __shfl_xor(lg[e], ofs, 64);
  }
  int be = 0;
  float bv = lg[0];
#pragma unroll
  for (int e = 1; e < NEXP; e++) {
    if (lg[e] > bv) { bv = lg[e]; be = e; }
  }
  float score = 1.f / (1.f + __expf(-bv));
  if (lane == 0) {
    expert_id[t] = be;
    slot[t] = atomicAdd(&counts[be], 1);
  }
#pragma unroll
  for (int p = 0; p < 4; p++) {
    short4v b, bs;
#pragma unroll
    for (int c = 0; c < 4; c++) {
      b[c] = f2bf(xv[p][c]);
      bs[c] = f2bf(xv[p][c] * score);
    }
    *(short4v*)(xbf + (size_t)t * HDIM + p * 256 + lane * 4) = b;
    *(short4v*)(xsbf + (size_t)t * HDIM + p * 256 + lane * 4) = bs;
  }
}

__global__ void prefix_kernel(const int* __restrict__ counts, int* __restrict__ pad_off) {
  if (threadIdx.x == 0 && blockIdx.x == 0) {
    int run = 0;
    for (int e = 0; e < NEXP; e++) {
      pad_off[e] = run;
      run += (counts[e] + BM - 1) & ~(BM - 1);
    }
    pad_off[NEXP] = run;
  }
}

__global__ __launch_bounds__(256) void build_perm(
    const int* __restrict__ expert_id, const int* __restrict__ slot,
    const int* __restrict__ pad_off, int* __restrict__ perm) {
  int t = blockIdx.x * 256 + threadIdx.x;
  int e = expert_id[t];
  perm[pad_off[e] + slot[t]] = t;
}

// ---------------------------------------------------------------- weight transpose+convert
// Wide-granularity LDS transpose. Theory: prior versions (256B read segments
// @8KB stride, 64B writes) pinned at ~2.4 TB/s regardless of structure ->
// global segment granularity is the limiter, not LDS/VALU.
// Tile: 256 n-cols x 64 k-rows.
//   Reads : 64 rows x 1KB contiguous (one wave-instruction = one full row).
//   Writes: 256 output rows x 128B contiguous, 128B-aligned (full L2 lines).
// LDS [64][260] bf16 (row stride 520B, 8B-aligned for b64 staging writes;
// staging = consecutive 8B per lane -> conflict-free). Column reads are
// scalar ds_read_u16 with moderate conflicts -- proven non-limiting (R2:
// VALUBusy 7.5%, mem-bound at 2.5TB/s with worse layout).
// Grid: w1 (src[1024][2048]->dst[2048][1024]): 8 n-tiles x 16 k-tiles = 128/matrix, 18 matrices
//       w2 (src[2048][1024]->dst[1024][2048]): 4 n-tiles x 32 k-tiles = 128/matrix, 9 matrices

__global__ __launch_bounds__(256) void transpose_all(
    const float* __restrict__ shg, const float* __restrict__ shu,
    const float* __restrict__ rtg, const float* __restrict__ rtu,
    short* __restrict__ shg_t, short* __restrict__ shu_t,
    short* __restrict__ rtg_t, short* __restrict__ rtu_t,
    const float* __restrict__ shd, const float* __restrict__ rtd,
    short* __restrict__ shd_t, short* __restrict__ rtd_t) {
  __shared__ __align__(16) short t[64][260];
  int bid = blockIdx.x;
  int tid = threadIdx.x;
  const float* s;
  short* d;
  int R, C, n0, k0;
  if (bid < 18 * 128) {
    int m = bid >> 7, w = bid & 127;
    R = HDIM; C = IDIM;                 // src [R][C], dst [C][R]
    if (m == 0)      { s = shg; d = shg_t; }
    else if (m == 1) { s = shu; d = shu_t; }
    else if (m < 10) { size_t o = (size_t)(m - 2) * HDIM * IDIM; s = rtg + o; d = rtg_t + o; }
    else             { size_t o = (size_t)(m - 10) * HDIM * IDIM; s = rtu + o; d = rtu_t + o; }
    n0 = (w >> 4) * 256;                // 8 n-tiles
    k0 = (w & 15) * 64;                 // 16 k-tiles
  } else {
    int b2 = bid - 18 * 128;
    int m = b2 >> 7, w = b2 & 127;
    R = IDIM; C = HDIM;
    if (m == 0) { s = shd; d = shd_t; }
    else        { size_t o = (size_t)(m - 1) * IDIM * HDIM; s = rtd + o; d = rtd_t + o; }
    n0 = (w >> 5) * 256;                // 4 n-tiles
    k0 = (w & 31) * 64;                 // 32 k-tiles
  }
  // stage: 16 iters; per iter the whole wave reads ONE full 1KB source row.
  // flat = j*256 + tid; row = flat>>6 (0..63), chunk = flat&63 (float4 idx).
  float4v v[16];
#pragma unroll
  for (int j = 0; j < 16; j++) {
    int row = j * 4 + (tid >> 6);
    int chunk = tid & 63;
    v[j] = *(const float4v*)(s + (size_t)(k0 + row) * C + n0 + chunk * 4);
  }
#pragma unroll
  for (int j = 0; j < 16; j++) {
    int row = j * 4 + (tid >> 6);
    int chunk = tid & 63;
    short4v b;
#pragma unroll
    for (int c = 0; c < 4; c++) b[c] = f2bf(v[j][c]);
    *(short4v*)(&t[row][chunk * 4]) = b;   // 8B store, 8B-aligned (row stride 520B)
  }
  __syncthreads();
  // drain: 8 iters; flat = j*256 + tid; n = flat>>3 (0..255), kc = (flat&7)*8.
  // 8 lanes cover one output row's 64 k (128B contiguous, 128B-aligned).
#pragma unroll
  for (int j = 0; j < 8; j++) {
    int flat = j * 256 + tid;
    int n = flat >> 3, kc = (flat & 7) * 8;
    short8 o;
#pragma unroll
    for (int i = 0; i < 8; i++) o[i] = t[kc + i][n];
    *(short8*)(d + (size_t)(n0 + n) * R + k0 + kc) = o;
  }
}

// ---------------------------------------------------------------- gemm1: act = silu(A Wg) * (A Wu)
// A bf16 [rows][1024]; B^T bf16 [2048 n][1024 k].
// 512 threads / 8 waves (2x4), wave owns 64x32 -> dual acc = 64 VGPR.
// 3-buffer K-pipeline, counted vmcnt(3) + raw s_barrier: loads stay 2 K-steps
// in flight, never drained in the loop (T3+T4). One barrier per K-step.
// setprio around MFMA (T5).
// grid y: [0,16) shared tiles, [16,40) routed padded tiles.

#define G1_STAGE(b, kk) do { \
    gload_lds16(A + gA + (kk), sA[b] + tid * 8);   \
    gload_lds16(Bg + gB + (kk), sBg[b] + tid * 8); \
    gload_lds16(Bu + gB + (kk), sBu[b] + tid * 8); } while (0)

__global__ __launch_bounds__(512, 2) void gemm1_swiglu(
    const short* __restrict__ xbf, const short* __restrict__ xsbf,
    const short* __restrict__ shg_t, const short* __restrict__ shu_t,
    const short* __restrict__ rtg_t, const short* __restrict__ rtu_t,
    short* __restrict__ act_sh, short* __restrict__ act_rt,
    const int* __restrict__ pad_off, const int* __restrict__ perm) {
  __shared__ __align__(1024) short sA[3][BM * BK1];
  __shared__ __align__(1024) short sBg[3][BM * BK1];
  __shared__ __align__(1024) short sBu[3][BM * BK1];
  int tid = threadIdx.x, lane = tid & 63, wv = tid >> 6;
  int C0 = blockIdx.x * 128;
  int y = blockIdx.y;
  const short *A, *Bg, *Bu;
  short* act;
  int R0;
  bool routed = (y >= SH_TILES);
  if (!routed) {
    A = xbf; Bg = shg_t; Bu = shu_t; act = act_sh; R0 = y * BM;
  } else {
    R0 = (y - SH_TILES) * BM;
    if (R0 >= pad_off[NEXP]) return;
    int e = 0;
    while (pad_off[e + 1] <= R0) e++;
    size_t o = (size_t)e * HDIM * IDIM;
    A = xsbf; Bg = rtg_t + o; Bu = rtu_t + o; act = act_rt;
  }
  // staging: tile = 512 chunks of 16B, one chunk per thread per tile.
  int c0 = swz(tid);
  int r0c = c0 >> 2;
  int ar0 = routed ? perm[R0 + r0c] : R0 + r0c;
  size_t gA = (size_t)ar0 * HDIM + (c0 & 3) * 8;
  size_t gB = (size_t)(C0 + r0c) * HDIM + (c0 & 3) * 8;

  float4v accg[4][2], accu[4][2];
  float4v z4 = {0.f, 0.f, 0.f, 0.f};
#pragma unroll
  for (int i = 0; i < 4; i++)
#pragma unroll
    for (int j = 0; j < 2; j++) { accg[i][j] = z4; accu[i][j] = z4; }

  const int wrow = (wv >> 2) * 64, wcol = (wv & 3) * 32;
  const int mrow = lane & 15, h4 = lane >> 4;
  int aoff[4], boff[2];
#pragma unroll
  for (int i = 0; i < 4; i++)
    aoff[i] = swz(((wrow + i * 16 + mrow) << 2) + h4) * 8;
#pragma unroll
  for (int j = 0; j < 2; j++)
    boff[j] = swz(((wcol + j * 16 + mrow) << 2) + h4) * 8;

  // prologue: 2 K-steps in flight
  G1_STAGE(0, 0);
  G1_STAGE(1, BK1);

  int cur = 0;
  for (int k0 = 0; k0 < HDIM; k0 += BK1) {
    if (k0 + BK1 < HDIM) {
      asm volatile("s_waitcnt vmcnt(3)" ::: "memory");   // this step's stage done
    } else {
      asm volatile("s_waitcnt vmcnt(0)" ::: "memory");   // final: drain
    }
    __builtin_amdgcn_s_barrier();
    int k2 = k0 + 2 * BK1;
    if (k2 < HDIM) {
      int nb = cur + 2; if (nb >= 3) nb -= 3;
      G1_STAGE(nb, k2);               // overwrites buf last read at iter-1; safe after barrier
    }
    const short* cA = sA[cur];
    const short* cG = sBg[cur];
    const short* cU = sBu[cur];
    short8 af[4], bg[2], bu[2];
#pragma unroll
    for (int i = 0; i < 4; i++) af[i] = *(const short8*)(cA + aoff[i]);
#pragma unroll
    for (int j = 0; j < 2; j++) {
      bg[j] = *(const short8*)(cG + boff[j]);
      bu[j] = *(const short8*)(cU + boff[j]);
    }
    __builtin_amdgcn_s_setprio(1);
#pragma unroll
    for (int i = 0; i < 4; i++)
#pragma unroll
      for (int j = 0; j < 2; j++) {
        accg[i][j] = __builtin_amdgcn_mfma_f32_16x16x32_bf16(af[i], bg[j], accg[i][j], 0, 0, 0);
        accu[i][j] = __builtin_amdgcn_mfma_f32_16x16x32_bf16(af[i], bu[j], accu[i][j], 0, 0, 0);
      }
    __builtin_amdgcn_s_setprio(0);
    cur = (cur == 2) ? 0 : cur + 1;
  }
  int qrow = h4 * 4, col = mrow;
#pragma unroll
  for (int i = 0; i < 4; i++)
#pragma unroll
    for (int j = 0; j < 2; j++)
#pragma unroll
      for (int r = 0; r < 4; r++) {
        int row = R0 + wrow + i * 16 + qrow + r;
        int c = C0 + wcol + j * 16 + col;
        float g = accg[i][j][r], u = accu[i][j][r];
        float sv = g / (1.f + __expf(-g)) * u;
        act[(size_t)row * IDIM + c] = f2bf(sv);
      }
}

// ---------------------------------------------------------------- gemm2: out = act Wd^T-form
// A bf16 [rows][2048]; B^T bf16 [1024 n][2048 k]. 256 thr / 4 waves, tile
// 128x64, BK=32, same 3-buffer counted-vmcnt pipeline.
// shared tiles -> plain store to out; routed -> scatter to rt_out; add kernel combines.

#define G2_STAGE(b, kk) do { \
    gload_lds16(A + gA0 + (kk), sA[b] + tid * 8);         \
    gload_lds16(A + gA1 + (kk), sA[b] + (tid + 256) * 8); \
    gload_lds16(Bd + gB0 + (kk), sB[b] + tid * 8); } while (0)

__global__ __launch_bounds__(256, 4) void gemm2_down(
    const short* __restrict__ act_sh, const short* __restrict__ act_rt,
    const short* __restrict__ shd_t, const short* __restrict__ rtd_t,
    float* __restrict__ out, float* __restrict__ rt_out,
    const int* __restrict__ pad_off, const int* __restrict__ counts,
    const int* __restrict__ perm) {
  __shared__ __align__(1024) short sA[3][BM * BK2];
  __shared__ __align__(1024) short sB[3][BN2 * BK2];
  int tid = threadIdx.x, lane = tid & 63, wv = tid >> 6;
  int C0 = blockIdx.x * BN2;
  int y = blockIdx.y;
  const short *A, *Bd;
  int R0, e = 0;
  bool routed = (y >= SH_TILES);
  if (!routed) {
    A = act_sh; Bd = shd_t; R0 = y * BM;
  } else {
    R0 = (y - SH_TILES) * BM;
    if (R0 >= pad_off[NEXP]) return;
    while (pad_off[e + 1] <= R0) e++;
    A = act_rt; Bd = rtd_t + (size_t)e * IDIM * HDIM;
  }
  // A tile 128x32 = 512 chunks (2/thread); B tile 64x32 = 256 chunks (1/thread)
  int cA0 = swz(tid), cA1 = swz(tid + 256), cB = swz(tid);
  size_t gA0 = (size_t)(R0 + (cA0 >> 2)) * IDIM + (cA0 & 3) * 8;
  size_t gA1 = (size_t)(R0 + (cA1 >> 2)) * IDIM + (cA1 & 3) * 8;
  size_t gB0 = (size_t)(C0 + (cB >> 2)) * IDIM + (cB & 3) * 8;

  float4v acc[2][4];
  float4v z4 = {0.f, 0.f, 0.f, 0.f};
#pragma unroll
  for (int i = 0; i < 2; i++)
#pragma unroll
    for (int j = 0; j < 4; j++) acc[i][j] = z4;

  const int wrow = wv * 32;
  const int mrow = lane & 15, h4 = lane >> 4;
  int aoff[2], boff[4];
#pragma unroll
  for (int i = 0; i < 2; i++)
    aoff[i] = swz(((wrow + i * 16 + mrow) << 2) + h4) * 8;
#pragma unroll
  for (int j = 0; j < 4; j++)
    boff[j] = swz(((j * 16 + mrow) << 2) + h4) * 8;

  G2_STAGE(0, 0);
  G2_STAGE(1, BK2);

  int cur = 0;
  for (int k0 = 0; k0 < IDIM; k0 += BK2) {
    if (k0 + BK2 < IDIM) {
      asm volatile("s_waitcnt vmcnt(3)" ::: "memory");
    } else {
      asm volatile("s_waitcnt vmcnt(0)" ::: "memory");
    }
    __builtin_amdgcn_s_barrier();
    int k2 = k0 + 2 * BK2;
    if (k2 < IDIM) {
      int nb = cur + 2; if (nb >= 3) nb -= 3;
      G2_STAGE(nb, k2);
    }
    const short* cAp = sA[cur];
    const short* cBp = sB[cur];
    short8 af[2], bf4[4];
#pragma unroll
    for (int i = 0; i < 2; i++) af[i] = *(const short8*)(cAp + aoff[i]);
#pragma unroll
    for (int j = 0; j < 4; j++) bf4[j] = *(const short8*)(cBp + boff[j]);
    __builtin_amdgcn_s_setprio(1);
#pragma unroll
    for (int i = 0; i < 2; i++)
#pragma unroll
      for (int j = 0; j < 4; j++)
        acc[i][j] = __builtin_amdgcn_mfma_f32_16x16x32_bf16(af[i], bf4[j], acc[i][j], 0, 0, 0);
    __builtin_amdgcn_s_setprio(0);
    cur = (cur == 2) ? 0 : cur + 1;
  }
  int qrow = h4 * 4, col = mrow;
#pragma unroll
  for (int i = 0; i < 2; i++)
#pragma unroll
    for (int j = 0; j < 4; j++)
#pragma unroll
      for (int r = 0; r < 4; r++) {
        int row = R0 + wrow + i * 16 + qrow + r;
        int c = C0 + j * 16 + col;
        float v = acc[i][j][r];
        if (!routed) {
          out[(size_t)row * HDIM + c] = v;
        } else if (row - pad_off[e] < counts[e]) {
          rt_out[(size_t)perm[row] * HDIM + c] = v;
        }
      }
}

__global__ __launch_bounds__(256) void add_routed(float* __restrict__ out,
                                                  const float* __restrict__ rt_out) {
  size_t i = ((size_t)blockIdx.x * 256 + threadIdx.x) * 4;
  float4v a = *(const float4v*)(out + i);
  float4v b = *(const float4v*)(rt_out + i);
  a[0] += b[0]; a[1] += b[1]; a[2] += b[2]; a[3] += b[3];
  *(float4v*)(out + i) = a;
}

// ---------------------------------------------------------------- launch

extern "C" void kernel_launch(void* const* d_in, const int* in_sizes, int n_in,
                              void* d_out, int out_size, void* d_ws, size_t ws_size,
                              hipStream_t stream) {
  const float* x       = (const float*)d_in[0];
  const float* gate_w  = (const float*)d_in[1];
  const float* sh_gate = (const float*)d_in[2];
  const float* sh_up   = (const float*)d_in[3];
  const float* sh_down = (const float*)d_in[4];
  const float* rt_gate = (const float*)d_in[5];
  const float* rt_up   = (const float*)d_in[6];
  const float* rt_down = (const float*)d_in[7];
  float* out = (float*)d_out;

  char* w = (char*)d_ws;
  const size_t MB = 1024 * 1024;
  short* xbf    = (short*)(w + 0 * MB);    // 4 MB  [2048][1024] bf16
  short* xsbf   = (short*)(w + 4 * MB);    // 4 MB
  short* act_sh = (short*)(w + 8 * MB);    // 8 MB  [2048][2048]
  short* act_rt = (short*)(w + 16 * MB);   // 12 MB [3072][2048]
  float* rt_out = (float*)(w + 28 * MB);   // 8 MB  [2048][1024] fp32
  short* shg_t  = (short*)(w + 36 * MB);   // 4 MB  [2048][1024]
  short* shu_t  = (short*)(w + 40 * MB);   // 4 MB
  short* shd_t  = (short*)(w + 44 * MB);   // 4 MB  [1024][2048]
  short* rtg_t  = (short*)(w + 48 * MB);   // 32 MB [8][2048][1024]
  short* rtu_t  = (short*)(w + 80 * MB);   // 32 MB
  short* rtd_t  = (short*)(w + 112 * MB);  // 32 MB [8][1024][2048]
  int* ints     = (int*)(w + 144 * MB);
  int* counts    = ints;
  int* pad_off   = ints + 8;
  int* expert_id = ints + 32;
  int* slot      = ints + 32 + 2048;
  int* perm      = ints + 32 + 4096;

  zero_init<<<1, 256, 0, stream>>>(counts, perm);
  router_kernel<<<T_TOK / 4, 256, 0, stream>>>(x, gate_w, xbf, xsbf, expert_id, slot, counts);
  prefix_kernel<<<1, 64, 0, stream>>>(counts, pad_off);
  build_perm<<<T_TOK / 256, 256, 0, stream>>>(expert_id, slot, pad_off, perm);

  transpose_all<<<18 * 128 + 9 * 128, 256, 0, stream>>>(
      sh_gate, sh_up, rt_gate, rt_up, shg_t, shu_t, rtg_t, rtu_t,
      sh_down, rt_down, shd_t, rtd_t);

  gemm1_swiglu<<<dim3(IDIM / 128, SH_TILES + RT_TILES), 512, 0, stream>>>(
      xbf, xsbf, shg_t, shu_t, rtg_t, rtu_t, act_sh, act_rt, pad_off, perm);

  gemm2_down<<<dim3(HDIM / BN2, SH_TILES + RT_TILES), 256, 0, stream>>>(
      act_sh, act_rt, shd_t, rtd_t, out, rt_out, pad_off, counts, perm);

  add_routed<<<(T_TOK * HDIM) / (256 * 4), 256, 0, stream>>>(out, rt_out);
}

// Round 7
// 406.819 us; speedup vs baseline: 1.0159x; 1.0130x over previous
//
#include <hip/hip_runtime.h>
#include <cstdint>
#include <cstddef>

// B=2,S=1024 -> T=2048 tokens
#define T_TOK 2048
#define HDIM  1024
#define IDIM  2048
#define NEXP  8

#define BM 128
#define BK1 32          // gemm1 K-tile
#define BK2 32          // gemm2 K-tile
#define BN2 64          // gemm2 col tile
#define MAXPAD 3072
#define SH_TILES 16     // T_TOK/BM
#define RT_TILES 24     // MAXPAD/BM

typedef __attribute__((ext_vector_type(8))) short short8;
typedef __attribute__((ext_vector_type(4))) short short4v;
typedef __attribute__((ext_vector_type(4))) float float4v;

__device__ __forceinline__ short f2bf(float f) {
  uint32_t u = __float_as_uint(f);
  u += 0x7fffu + ((u >> 16) & 1u);
  return (short)(u >> 16);
}

__device__ __forceinline__ void gload_lds16(const void* g, void* l) {
  __builtin_amdgcn_global_load_lds(
      (const __attribute__((address_space(1))) uint32_t*)g,
      (__attribute__((address_space(3))) uint32_t*)l, 16, 0, 0);
}

// 16B-chunk XOR swizzle (self-inverse): bits[1:0] ^= bits[5:4].
__device__ __forceinline__ int swz(int c) { return c ^ ((c >> 4) & 3); }

// ---------------------------------------------------------------- small kernels

__global__ __launch_bounds__(256) void zero_init(int* __restrict__ counts,
                                                 int* __restrict__ perm) {
  int i = threadIdx.x;
  if (i < NEXP) counts[i] = 0;
  for (int p = i; p < MAXPAD; p += 256) perm[p] = 0;
}

// one wave per token: fp32 logits (exact argmax vs ref), score, bf16 copies
__global__ __launch_bounds__(256) void router_kernel(
    const float* __restrict__ x, const float* __restrict__ gw,
    short* __restrict__ xbf, short* __restrict__ xsbf,
    int* __restrict__ expert_id, int* __restrict__ slot,
    int* __restrict__ counts) {
  int wv = threadIdx.x >> 6, lane = threadIdx.x & 63;
  int t = blockIdx.x * 4 + wv;
  const float* xr = x + (size_t)t * HDIM;
  float4v xv[4];
  float lg[NEXP];
#pragma unroll
  for (int e = 0; e < NEXP; e++) lg[e] = 0.f;
#pragma unroll
  for (int p = 0; p < 4; p++) {
    xv[p] = *(const float4v*)(xr + p * 256 + lane * 4);
#pragma unroll
    for (int c = 0; c < 4; c++) {
      int h = p * 256 + lane * 4 + c;
      float4v g0 = *(const float4v*)(gw + (size_t)h * NEXP);
      float4v g1 = *(const float4v*)(gw + (size_t)h * NEXP + 4);
      float xc = xv[p][c];
      lg[0] += xc * g0[0]; lg[1] += xc * g0[1];
      lg[2] += xc * g0[2]; lg[3] += xc * g0[3];
      lg[4] += xc * g1[0]; lg[5] += xc * g1[1];
      lg[6] += xc * g1[2]; lg[7] += xc * g1[3];
    }
  }
#pragma unroll
  for (int ofs = 1; ofs < 64; ofs <<= 1) {
#pragma unroll
    for (int e = 0; e < NEXP; e++) lg[e] += __shfl_xor(lg[e], ofs, 64);
  }
  int be = 0;
  float bv = lg[0];
#pragma unroll
  for (int e = 1; e < NEXP; e++) {
    if (lg[e] > bv) { bv = lg[e]; be = e; }
  }
  float score = 1.f / (1.f + __expf(-bv));
  if (lane == 0) {
    expert_id[t] = be;
    slot[t] = atomicAdd(&counts[be], 1);
  }
#pragma unroll
  for (int p = 0; p < 4; p++) {
    short4v b, bs;
#pragma unroll
    for (int c = 0; c < 4; c++) {
      b[c] = f2bf(xv[p][c]);
      bs[c] = f2bf(xv[p][c] * score);
    }
    *(short4v*)(xbf + (size_t)t * HDIM + p * 256 + lane * 4) = b;
    *(short4v*)(xsbf + (size_t)t * HDIM + p * 256 + lane * 4) = bs;
  }
}

__global__ void prefix_kernel(const int* __restrict__ counts, int* __restrict__ pad_off) {
  if (threadIdx.x == 0 && blockIdx.x == 0) {
    int run = 0;
    for (int e = 0; e < NEXP; e++) {
      pad_off[e] = run;
      run += (counts[e] + BM - 1) & ~(BM - 1);
    }
    pad_off[NEXP] = run;
  }
}

__global__ __launch_bounds__(256) void build_perm(
    const int* __restrict__ expert_id, const int* __restrict__ slot,
    const int* __restrict__ pad_off, int* __restrict__ perm) {
  int t = blockIdx.x * 256 + threadIdx.x;
  int e = expert_id[t];
  perm[pad_off[e] + slot[t]] = t;
}

// ---------------------------------------------------------------- weight transpose+convert
// BLOCKED-layout transpose. Evidence: R2/R4/R5 transposes all pin at 2.3-2.5
// TB/s across read-seg 256B->1KB, write-seg 16->128B, bank-conflicts 0-5M,
// occupancy 34-73% => per-instruction granularity is NOT the limiter; the
// remaining shared trait is per-block scattered writes (strided 128B lines
// over ~1MB windows x 27 matrices). Fix: the GEMM's global_load_lds source
// address is per-lane-arbitrary, so W_t doesn't need row-major [n][k] -- use
// contiguous per-GEMM-staging-tile blobs:
//   gemm1 B: blob(nt,kt) = 128n x 32k = 4096 shorts at ((nt*32+kt)*4096);
//            chunk c (16B): n = nt*128 + (c>>2), k = kt*32 + (c&3)*8 + [0..8)
//   gemm2 B: blob(nt,kt) = 64n x 32k = 2048 shorts at ((nt*64+kt)*2048)
// Transpose block writes 16KB fully CONTIGUOUS (4KB per wave-instruction).
// Reads stay 512B/256B segments; LDS column-drain same as R1 (proven
// non-limiting, VALUBusy 7%).
// Grid: 18*256 w1 blocks (128n x 64k tiles) + 9*256 w2 blocks (64n x 128k).

__global__ __launch_bounds__(256) void transpose_all(
    const float* __restrict__ shg, const float* __restrict__ shu,
    const float* __restrict__ rtg, const float* __restrict__ rtu,
    short* __restrict__ shg_t, short* __restrict__ shu_t,
    short* __restrict__ rtg_t, short* __restrict__ rtu_t,
    const float* __restrict__ shd, const float* __restrict__ rtd,
    short* __restrict__ shd_t, short* __restrict__ rtd_t) {
  __shared__ short tl[8704];   // w1: [64][132] view; w2: [128][68] view
  int bid = blockIdx.x, t = threadIdx.x;
  if (bid < 18 * 256) {
    // w1: src fp32 [1024 k][2048 n]; tile = 128n x 64k = blobs (nt, ktp*2..+1)
    int m = bid >> 8, w = bid & 255;
    const float* s; short* d;
    if (m == 0)      { s = shg; d = shg_t; }
    else if (m == 1) { s = shu; d = shu_t; }
    else if (m < 10) { size_t o = (size_t)(m - 2) * HDIM * IDIM; s = rtg + o; d = rtg_t + o; }
    else             { size_t o = (size_t)(m - 10) * HDIM * IDIM; s = rtu + o; d = rtu_t + o; }
    int nt = w >> 4, ktp = w & 15;
    int n0 = nt * 128, k0 = ktp * 64;
    // load 64 rows x 512B (coalesced), convert, LDS [64][132]
#pragma unroll
    for (int j = 0; j < 8; j++) {
      int flat = j * 256 + t;
      int row = flat >> 5, c16 = flat & 31;
      float4v v = *(const float4v*)(s + (size_t)(k0 + row) * IDIM + n0 + c16 * 4);
      short4v b;
#pragma unroll
      for (int c = 0; c < 4; c++) b[c] = f2bf(v[c]);
      *(short4v*)(&tl[row * 132 + c16 * 4]) = b;
    }
    __syncthreads();
    // drain: 1024 chunks = 2 blobs, written fully contiguous
#pragma unroll
    for (int j = 0; j < 4; j++) {
      int c2 = j * 256 + t;
      int kt2 = c2 >> 9, c = c2 & 511;
      int n = c >> 2, kg = c & 3;
      short8 o;
#pragma unroll
      for (int i = 0; i < 8; i++) o[i] = tl[(kt2 * 32 + kg * 8 + i) * 132 + n];
      *(short8*)(d + (size_t)(nt * 32 + ktp * 2 + kt2) * 4096 + (size_t)c * 8) = o;
    }
  } else {
    // w2: src fp32 [2048 k][1024 n]; tile = 64n x 128k = blobs (nt, ktq*4..+3)
    int b2 = bid - 18 * 256;
    int m = b2 >> 8, w = b2 & 255;
    const float* s; short* d;
    if (m == 0) { s = shd; d = shd_t; }
    else        { size_t o = (size_t)(m - 1) * IDIM * HDIM; s = rtd + o; d = rtd_t + o; }
    int nt = w >> 4, ktq = w & 15;
    int n0 = nt * 64, k0 = ktq * 128;
#pragma unroll
    for (int j = 0; j < 8; j++) {
      int flat = j * 256 + t;
      int row = flat >> 4, c16 = flat & 15;
      float4v v = *(const float4v*)(s + (size_t)(k0 + row) * HDIM + n0 + c16 * 4);
      short4v b;
#pragma unroll
      for (int c = 0; c < 4; c++) b[c] = f2bf(v[c]);
      *(short4v*)(&tl[row * 68 + c16 * 4]) = b;
    }
    __syncthreads();
#pragma unroll
    for (int j = 0; j < 4; j++) {
      int c2 = j * 256 + t;
      int kq2 = c2 >> 8, c = c2 & 255;
      int n = c >> 2, kg = c & 3;
      short8 o;
#pragma unroll
      for (int i = 0; i < 8; i++) o[i] = tl[(kq2 * 32 + kg * 8 + i) * 68 + n];
      *(short8*)(d + (size_t)(nt * 64 + ktq * 4 + kq2) * 2048 + (size_t)c * 8) = o;
    }
  }
}

// ---------------------------------------------------------------- gemm1: act = silu(A Wg) * (A Wu)
// A bf16 [rows][1024]; B blocked blobs (see transpose_all).
// 512 threads / 8 waves (2x4), wave owns 64x32 -> dual acc = 64 VGPR.
// 3-buffer K-pipeline, counted vmcnt(3) + raw s_barrier (T3+T4); setprio (T5).
// B staging is now a LINEAR blob scan: base + swz(tid)*8, step k0*128.
// grid y: [0,16) shared tiles, [16,40) routed padded tiles.

#define G1_STAGE(b, kk) do { \
    gload_lds16(A + gA + (kk), sA[b] + tid * 8);                    \
    gload_lds16(Bg + gB + (size_t)(kk) * 128, sBg[b] + tid * 8);    \
    gload_lds16(Bu + gB + (size_t)(kk) * 128, sBu[b] + tid * 8); } while (0)

__global__ __launch_bounds__(512, 2) void gemm1_swiglu(
    const short* __restrict__ xbf, const short* __restrict__ xsbf,
    const short* __restrict__ shg_t, const short* __restrict__ shu_t,
    const short* __restrict__ rtg_t, const short* __restrict__ rtu_t,
    short* __restrict__ act_sh, short* __restrict__ act_rt,
    const int* __restrict__ pad_off, const int* __restrict__ perm) {
  __shared__ __align__(1024) short sA[3][BM * BK1];
  __shared__ __align__(1024) short sBg[3][BM * BK1];
  __shared__ __align__(1024) short sBu[3][BM * BK1];
  int tid = threadIdx.x, lane = tid & 63, wv = tid >> 6;
  int y = blockIdx.y;
  const short *A, *Bg, *Bu;
  short* act;
  int R0;
  bool routed = (y >= SH_TILES);
  if (!routed) {
    A = xbf; Bg = shg_t; Bu = shu_t; act = act_sh; R0 = y * BM;
  } else {
    R0 = (y - SH_TILES) * BM;
    if (R0 >= pad_off[NEXP]) return;
    int e = 0;
    while (pad_off[e + 1] <= R0) e++;
    size_t o = (size_t)e * HDIM * IDIM;
    A = xsbf; Bg = rtg_t + o; Bu = rtu_t + o; act = act_rt;
  }
  int C0 = blockIdx.x * 128;
  // A staging: chunk c0 = swz(tid): row = c0>>2, koff = (c0&3)*8 (row-major).
  int c0 = swz(tid);
  int r0c = c0 >> 2;
  int ar0 = routed ? perm[R0 + r0c] : R0 + r0c;
  size_t gA = (size_t)ar0 * HDIM + (c0 & 3) * 8;
  // B staging: blob(nt = blockIdx.x, kt = k0/32); chunk swz(tid) within blob.
  size_t gB = (size_t)blockIdx.x * 32 * 4096 + (size_t)c0 * 8;

  float4v accg[4][2], accu[4][2];
  float4v z4 = {0.f, 0.f, 0.f, 0.f};
#pragma unroll
  for (int i = 0; i < 4; i++)
#pragma unroll
    for (int j = 0; j < 2; j++) { accg[i][j] = z4; accu[i][j] = z4; }

  const int wrow = (wv >> 2) * 64, wcol = (wv & 3) * 32;
  const int mrow = lane & 15, h4 = lane >> 4;
  int aoff[4], boff[2];
#pragma unroll
  for (int i = 0; i < 4; i++)
    aoff[i] = swz(((wrow + i * 16 + mrow) << 2) + h4) * 8;
#pragma unroll
  for (int j = 0; j < 2; j++)
    boff[j] = swz(((wcol + j * 16 + mrow) << 2) + h4) * 8;

  // prologue: 2 K-steps in flight
  G1_STAGE(0, 0);
  G1_STAGE(1, BK1);

  int cur = 0;
  for (int k0 = 0; k0 < HDIM; k0 += BK1) {
    if (k0 + BK1 < HDIM) {
      asm volatile("s_waitcnt vmcnt(3)" ::: "memory");   // this step's stage done
    } else {
      asm volatile("s_waitcnt vmcnt(0)" ::: "memory");   // final: drain
    }
    __builtin_amdgcn_s_barrier();
    int k2 = k0 + 2 * BK1;
    if (k2 < HDIM) {
      int nb = cur + 2; if (nb >= 3) nb -= 3;
      G1_STAGE(nb, k2);               // overwrites buf last read at iter-1; safe after barrier
    }
    const short* cA = sA[cur];
    const short* cG = sBg[cur];
    const short* cU = sBu[cur];
    short8 af[4], bg[2], bu[2];
#pragma unroll
    for (int i = 0; i < 4; i++) af[i] = *(const short8*)(cA + aoff[i]);
#pragma unroll
    for (int j = 0; j < 2; j++) {
      bg[j] = *(const short8*)(cG + boff[j]);
      bu[j] = *(const short8*)(cU + boff[j]);
    }
    __builtin_amdgcn_s_setprio(1);
#pragma unroll
    for (int i = 0; i < 4; i++)
#pragma unroll
      for (int j = 0; j < 2; j++) {
        accg[i][j] = __builtin_amdgcn_mfma_f32_16x16x32_bf16(af[i], bg[j], accg[i][j], 0, 0, 0);
        accu[i][j] = __builtin_amdgcn_mfma_f32_16x16x32_bf16(af[i], bu[j], accu[i][j], 0, 0, 0);
      }
    __builtin_amdgcn_s_setprio(0);
    cur = (cur == 2) ? 0 : cur + 1;
  }
  int qrow = h4 * 4, col = mrow;
#pragma unroll
  for (int i = 0; i < 4; i++)
#pragma unroll
    for (int j = 0; j < 2; j++)
#pragma unroll
      for (int r = 0; r < 4; r++) {
        int row = R0 + wrow + i * 16 + qrow + r;
        int c = C0 + wcol + j * 16 + col;
        float g = accg[i][j][r], u = accu[i][j][r];
        float sv = g / (1.f + __expf(-g)) * u;
        act[(size_t)row * IDIM + c] = f2bf(sv);
      }
}

// ---------------------------------------------------------------- gemm2: out = act Wd^T-form
// A bf16 [rows][2048]; B blocked blobs (64n x 32k). 256 thr / 4 waves, tile
// 128x64, BK=32, same 3-buffer counted-vmcnt pipeline.
// shared tiles -> plain store to out; routed -> scatter to rt_out; add kernel combines.

#define G2_STAGE(b, kk) do { \
    gload_lds16(A + gA0 + (kk), sA[b] + tid * 8);         \
    gload_lds16(A + gA1 + (kk), sA[b] + (tid + 256) * 8); \
    gload_lds16(Bd + gB0 + (size_t)(kk) * 64, sB[b] + tid * 8); } while (0)

__global__ __launch_bounds__(256, 4) void gemm2_down(
    const short* __restrict__ act_sh, const short* __restrict__ act_rt,
    const short* __restrict__ shd_t, const short* __restrict__ rtd_t,
    float* __restrict__ out, float* __restrict__ rt_out,
    const int* __restrict__ pad_off, const int* __restrict__ counts,
    const int* __restrict__ perm) {
  __shared__ __align__(1024) short sA[3][BM * BK2];
  __shared__ __align__(1024) short sB[3][BN2 * BK2];
  int tid = threadIdx.x, lane = tid & 63, wv = tid >> 6;
  int C0 = blockIdx.x * BN2;
  int y = blockIdx.y;
  const short *A, *Bd;
  int R0, e = 0;
  bool routed = (y >= SH_TILES);
  if (!routed) {
    A = act_sh; Bd = shd_t; R0 = y * BM;
  } else {
    R0 = (y - SH_TILES) * BM;
    if (R0 >= pad_off[NEXP]) return;
    while (pad_off[e + 1] <= R0) e++;
    A = act_rt; Bd = rtd_t + (size_t)e * IDIM * HDIM;
  }
  // A tile 128x32 = 512 chunks (2/thread, row-major act); B = blob scan.
  int cA0 = swz(tid), cA1 = swz(tid + 256), cB = swz(tid);
  size_t gA0 = (size_t)(R0 + (cA0 >> 2)) * IDIM + (cA0 & 3) * 8;
  size_t gA1 = (size_t)(R0 + (cA1 >> 2)) * IDIM + (cA1 & 3) * 8;
  size_t gB0 = (size_t)blockIdx.x * 64 * 2048 + (size_t)cB * 8;

  float4v acc[2][4];
  float4v z4 = {0.f, 0.f, 0.f, 0.f};
#pragma unroll
  for (int i = 0; i < 2; i++)
#pragma unroll
    for (int j = 0; j < 4; j++) acc[i][j] = z4;

  const int wrow = wv * 32;
  const int mrow = lane & 15, h4 = lane >> 4;
  int aoff[2], boff[4];
#pragma unroll
  for (int i = 0; i < 2; i++)
    aoff[i] = swz(((wrow + i * 16 + mrow) << 2) + h4) * 8;
#pragma unroll
  for (int j = 0; j < 4; j++)
    boff[j] = swz(((j * 16 + mrow) << 2) + h4) * 8;

  G2_STAGE(0, 0);
  G2_STAGE(1, BK2);

  int cur = 0;
  for (int k0 = 0; k0 < IDIM; k0 += BK2) {
    if (k0 + BK2 < IDIM) {
      asm volatile("s_waitcnt vmcnt(3)" ::: "memory");
    } else {
      asm volatile("s_waitcnt vmcnt(0)" ::: "memory");
    }
    __builtin_amdgcn_s_barrier();
    int k2 = k0 + 2 * BK2;
    if (k2 < IDIM) {
      int nb = cur + 2; if (nb >= 3) nb -= 3;
      G2_STAGE(nb, k2);
    }
    const short* cAp = sA[cur];
    const short* cBp = sB[cur];
    short8 af[2], bf4[4];
#pragma unroll
    for (int i = 0; i < 2; i++) af[i] = *(const short8*)(cAp + aoff[i]);
#pragma unroll
    for (int j = 0; j < 4; j++) bf4[j] = *(const short8*)(cBp + boff[j]);
    __builtin_amdgcn_s_setprio(1);
#pragma unroll
    for (int i = 0; i < 2; i++)
#pragma unroll
      for (int j = 0; j < 4; j++)
        acc[i][j] = __builtin_amdgcn_mfma_f32_16x16x32_bf16(af[i], bf4[j], acc[i][j], 0, 0, 0);
    __builtin_amdgcn_s_setprio(0);
    cur = (cur == 2) ? 0 : cur + 1;
  }
  int qrow = h4 * 4, col = mrow;
#pragma unroll
  for (int i = 0; i < 2; i++)
#pragma unroll
    for (int j = 0; j < 4; j++)
#pragma unroll
      for (int r = 0; r < 4; r++) {
        int row = R0 + wrow + i * 16 + qrow + r;
        int c = C0 + j * 16 + col;
        float v = acc[i][j][r];
        if (!routed) {
          out[(size_t)row * HDIM + c] = v;
        } else if (row - pad_off[e] < counts[e]) {
          rt_out[(size_t)perm[row] * HDIM + c] = v;
        }
      }
}

__global__ __launch_bounds__(256) void add_routed(float* __restrict__ out,
                                                  const float* __restrict__ rt_out) {
  size_t i = ((size_t)blockIdx.x * 256 + threadIdx.x) * 4;
  float4v a = *(const float4v*)(out + i);
  float4v b = *(const float4v*)(rt_out + i);
  a[0] += b[0]; a[1] += b[1]; a[2] += b[2]; a[3] += b[3];
  *(float4v*)(out + i) = a;
}

// ---------------------------------------------------------------- launch

extern "C" void kernel_launch(void* const* d_in, const int* in_sizes, int n_in,
                              void* d_out, int out_size, void* d_ws, size_t ws_size,
                              hipStream_t stream) {
  const float* x       = (const float*)d_in[0];
  const float* gate_w  = (const float*)d_in[1];
  const float* sh_gate = (const float*)d_in[2];
  const float* sh_up   = (const float*)d_in[3];
  const float* sh_down = (const float*)d_in[4];
  const float* rt_gate = (const float*)d_in[5];
  const float* rt_up   = (const float*)d_in[6];
  const float* rt_down = (const float*)d_in[7];
  float* out = (float*)d_out;

  char* w = (char*)d_ws;
  const size_t MB = 1024 * 1024;
  short* xbf    = (short*)(w + 0 * MB);    // 4 MB  [2048][1024] bf16
  short* xsbf   = (short*)(w + 4 * MB);    // 4 MB
  short* act_sh = (short*)(w + 8 * MB);    // 8 MB  [2048][2048]
  short* act_rt = (short*)(w + 16 * MB);   // 12 MB [3072][2048]
  float* rt_out = (float*)(w + 28 * MB);   // 8 MB  [2048][1024] fp32
  short* shg_t  = (short*)(w + 36 * MB);   // 4 MB  blocked blobs
  short* shu_t  = (short*)(w + 40 * MB);   // 4 MB
  short* shd_t  = (short*)(w + 44 * MB);   // 4 MB
  short* rtg_t  = (short*)(w + 48 * MB);   // 32 MB [8] x blocked
  short* rtu_t  = (short*)(w + 80 * MB);   // 32 MB
  short* rtd_t  = (short*)(w + 112 * MB);  // 32 MB
  int* ints     = (int*)(w + 144 * MB);
  int* counts    = ints;
  int* pad_off   = ints + 8;
  int* expert_id = ints + 32;
  int* slot      = ints + 32 + 2048;
  int* perm      = ints + 32 + 4096;

  zero_init<<<1, 256, 0, stream>>>(counts, perm);
  router_kernel<<<T_TOK / 4, 256, 0, stream>>>(x, gate_w, xbf, xsbf, expert_id, slot, counts);
  prefix_kernel<<<1, 64, 0, stream>>>(counts, pad_off);
  build_perm<<<T_TOK / 256, 256, 0, stream>>>(expert_id, slot, pad_off, perm);

  transpose_all<<<18 * 256 + 9 * 256, 256, 0, stream>>>(
      sh_gate, sh_up, rt_gate, rt_up, shg_t, shu_t, rtg_t, rtu_t,
      sh_down, rt_down, shd_t, rtd_t);

  gemm1_swiglu<<<dim3(IDIM / 128, SH_TILES + RT_TILES), 512, 0, stream>>>(
      xbf, xsbf, shg_t, shu_t, rtg_t, rtu_t, act_sh, act_rt, pad_off, perm);

  gemm2_down<<<dim3(HDIM / BN2, SH_TILES + RT_TILES), 256, 0, stream>>>(
      act_sh, act_rt, shd_t, rtd_t, out, rt_out, pad_off, counts, perm);

  add_routed<<<(T_TOK * HDIM) / (256 * 4), 256, 0, stream>>>(out, rt_out);
}